// Round 1
// 1350.178 us; speedup vs baseline: 2.0942x; 2.0942x over previous
//
#include <hip/hip_runtime.h>
#include <hip/hip_fp16.h>

#define D 128
#define R 8            // rows per block-iteration
#define TRIG 4e-6f     // fp64-recompute trigger (fast fp32 path error ~1.5e-7 << this)
#define REL_W 2e-6     // blend band half-width, relative to |boundary|
#define TS 0.3         // plateau fraction of band: |t|<TS -> 50/50 blend

// One block = 256 threads. Per iteration, 8 rows are processed together:
//   phase 1 : coalesced float4 load of 8 rows + fp64 norm^2 reduce (32 lanes/row)
//   phase 1b: threads 0..7 compute per-row {den, 1/den, correctly-rounded fp16}
//             (overlapped with phase 2 in the other waves; no extra barrier)
//   phase 2 : forward half-dots (fp32, Pi cached in registers)
//   phase 3 : fp32 binning; coords within TRIG of a boundary take the exact
//             fp64 recompute + blend path (identical to previous kernel)
//   phase 4 : recon half-dots
//   phase 5 : coalesced float4 store scaled by fp16-rounded norm
// 4 barriers per 8 rows (was 4+ per row).
__global__ __launch_bounds__(256) void tq_kernel(
    const float* __restrict__ x, const float* __restrict__ Pi,
    const float* __restrict__ centroids, const float* __restrict__ boundaries,
    float* __restrict__ out, int n_rows)
{
    __shared__ __align__(16) float xbuf[R][D];      // current rows (exact fp32 input)
    __shared__ __align__(16) float qbuf[R][D];      // (blended) centroids per coord
    __shared__ __align__(16) float fpart[2][R][D];  // forward partial dots
    __shared__ __align__(16) float rpart[2][R][D];  // recon partial dots
    __shared__ double s_norm2[R];
    __shared__ double s_dend[R];                    // norm + 1e-8 (fp64, slow path)
    __shared__ float  s_invnf[R];                   // (float)(1/den) for fast path
    __shared__ float  s_n16[R];                     // correctly-rounded fp16 norm
    __shared__ float  cbuf[16];                     // centroids
    __shared__ float  fbp[17];                      // padded inner boundaries (fp32)
    __shared__ double dbuf[15];                     // inner boundaries (fp64)

    const int tid = threadIdx.x;
    const int m  = tid & (D - 1);
    const int h  = tid >> 7;    // 0 or 1: which half of the D-dim
    const int lr = tid >> 5;    // 0..7: local row for load/store
    const int q  = tid & 31;    // float4 slot within row

    // ---- one-time per-block setup: cache Pi slices in registers ----
    float pf[64];   // Pi[m][h*64+i]      (forward rotate)
    float pr[64];   // Pi[h*64+i][m]      (reconstruction)
    {
        const float4* prow = (const float4*)(Pi + m * D + h * 64);
        #pragma unroll
        for (int i = 0; i < 16; ++i) {
            float4 v = prow[i];
            pf[4 * i + 0] = v.x; pf[4 * i + 1] = v.y;
            pf[4 * i + 2] = v.z; pf[4 * i + 3] = v.w;
        }
        #pragma unroll
        for (int i = 0; i < 64; ++i) pr[i] = Pi[(h * 64 + i) * D + m];
    }
    // inner boundaries, uniform -> expect s_load/SGPRs
    float bnd[15];
    #pragma unroll
    for (int i = 0; i < 15; ++i) bnd[i] = boundaries[i + 1];

    if (tid < 16) cbuf[tid] = centroids[tid];
    if (tid < 15) { dbuf[tid] = (double)boundaries[tid + 1]; fbp[tid + 1] = boundaries[tid + 1]; }
    if (tid == 0) { fbp[0] = -3.0e38f; fbp[16] = 3.0e38f; }
    __syncthreads();

    for (long long rb = (long long)blockIdx.x * R; rb < n_rows;
         rb += (long long)gridDim.x * R) {
        const int rvalid = (int)((n_rows - rb) < R ? (n_rows - rb) : R);
        const long long gbase = rb * D;

        // ---- phase 1: load 8 rows (float4, coalesced) + fp64 norm^2 ----
        double dp = 0.0;
        if (lr < rvalid) {
            float4 v = *(const float4*)(x + gbase + lr * D + q * 4);
            *(float4*)(&xbuf[lr][q * 4]) = v;
            dp = (double)v.x * v.x + (double)v.y * v.y
               + (double)v.z * v.z + (double)v.w * v.w;
        }
        #pragma unroll
        for (int off = 16; off; off >>= 1)
            dp += __shfl_down(dp, off, 32);
        if (q == 0 && lr < rvalid) s_norm2[lr] = dp;
        __syncthreads();

        // ---- phase 1b: per-row norm constants (threads 0..7 only) ----
        if (tid < rvalid) {
            double nrm = sqrt(s_norm2[tid]);
            double den = nrm + 1e-8;
            s_dend[tid]  = den;
            s_invnf[tid] = (float)(1.0 / den);
            // correctly-rounded fp64 -> fp16 (avoid double-rounding via fp32)
            __half h0 = __float2half((float)nrm);
            unsigned short hb = __half_as_ushort(h0);
            unsigned short bestb = hb;
            double bestd = fabs((double)__half2float(h0) - nrm);
            #pragma unroll
            for (int k = 0; k < 2; ++k) {
                unsigned short cb = (unsigned short)(k == 0 ? hb - 1 : hb + 1);
                double v2 = (double)__half2float(__ushort_as_half(cb));
                double dd = fabs(v2 - nrm);
                if (dd < bestd || (dd == bestd && ((cb & 1) == 0) && ((bestb & 1) == 1))) {
                    bestd = dd; bestb = cb;
                }
            }
            s_n16[tid] = __half2float(__ushort_as_half(bestb));
        }

        // ---- phase 2: forward half-dots, all 8 rows (x unscaled) ----
        for (int r = 0; r < R; ++r) {
            const float4* xb = (const float4*)(&xbuf[r][h * 64]);
            float a0 = 0.f, a1 = 0.f, a2 = 0.f, a3 = 0.f;
            #pragma unroll
            for (int i = 0; i < 16; ++i) {
                float4 u = xb[i];
                a0 = fmaf(u.x, pf[4 * i + 0], a0);
                a1 = fmaf(u.y, pf[4 * i + 1], a1);
                a2 = fmaf(u.z, pf[4 * i + 2], a2);
                a3 = fmaf(u.w, pf[4 * i + 3], a3);
            }
            fpart[h][r][m] = (a0 + a1) + (a2 + a3);
        }
        __syncthreads();

        // ---- phase 3: binning (fp32 fast path, fp64 guard preserved) ----
        #pragma unroll
        for (int j = 0; j < R / 2; ++j) {
            const int r = h + 2 * j;   // h=0 -> rows 0,2,4,6 ; h=1 -> 1,3,5,7
            const float rcf = (fpart[0][r][m] + fpart[1][r][m]) * s_invnf[r];
            int idx = 0;
            #pragma unroll
            for (int i = 0; i < 15; ++i) idx += (bnd[i] < rcf) ? 1 : 0;
            // nearest inner boundary is one of the two bracketing entries
            const float mind = fminf(rcf - fbp[idx], fbp[idx + 1] - rcf);
            float qv;
            if (__builtin_expect(mind < TRIG, 0)) {
                // exact fp64 recompute of this coordinate (rare: ~0.02%)
                double s = 0.0;
                const float* pim = Pi + m * D;
                for (int d2 = 0; d2 < D; ++d2)
                    s += (double)xbuf[r][d2] * (double)pim[d2];
                double rc = s / s_dend[r];
                int idx2 = 0; int ib = 0; double mind2 = 1e30;
                #pragma unroll
                for (int i = 0; i < 15; ++i) {
                    double b = dbuf[i];
                    idx2 += (b < rc) ? 1 : 0;
                    double dd = fabs(rc - b);
                    if (dd < mind2) { mind2 = dd; ib = i; }
                }
                double w = REL_W * fabs(dbuf[ib]);
                if (mind2 < w) {
                    // ambiguous zone: blend the two adjacent centroids
                    double t  = (rc - dbuf[ib]) / w;   // (-1, 1)
                    double at = fabs(t);
                    double u;
                    if (at <= TS) u = 0.5;
                    else {
                        double v2 = 0.5 * (at - TS) / (1.0 - TS);
                        u = (t > 0.0) ? 0.5 + v2 : 0.5 - v2;
                    }
                    qv = (float)((1.0 - u) * (double)cbuf[ib] + u * (double)cbuf[ib + 1]);
                } else {
                    qv = cbuf[idx2];
                }
            } else {
                qv = cbuf[idx];
            }
            qbuf[r][m] = qv;
        }
        __syncthreads();

        // ---- phase 4: recon half-dots, all 8 rows ----
        for (int r = 0; r < R; ++r) {
            const float4* qb = (const float4*)(&qbuf[r][h * 64]);
            float a0 = 0.f, a1 = 0.f, a2 = 0.f, a3 = 0.f;
            #pragma unroll
            for (int i = 0; i < 16; ++i) {
                float4 u = qb[i];
                a0 = fmaf(u.x, pr[4 * i + 0], a0);
                a1 = fmaf(u.y, pr[4 * i + 1], a1);
                a2 = fmaf(u.z, pr[4 * i + 2], a2);
                a3 = fmaf(u.w, pr[4 * i + 3], a3);
            }
            rpart[h][r][m] = (a0 + a1) + (a2 + a3);
        }
        __syncthreads();

        // ---- phase 5: scaled float4 store (coalesced) ----
        if (lr < rvalid) {
            const float n16 = s_n16[lr];
            float4 p0 = *(const float4*)(&rpart[0][lr][q * 4]);
            float4 p1 = *(const float4*)(&rpart[1][lr][q * 4]);
            float4 o;
            o.x = (p0.x + p1.x) * n16;
            o.y = (p0.y + p1.y) * n16;
            o.z = (p0.z + p1.z) * n16;
            o.w = (p0.w + p1.w) * n16;
            *(float4*)(out + gbase + lr * D + q * 4) = o;
        }
    }
}

extern "C" void kernel_launch(void* const* d_in, const int* in_sizes, int n_in,
                              void* d_out, int out_size, void* d_ws, size_t ws_size,
                              hipStream_t stream) {
    const float* x    = (const float*)d_in[0];
    const float* Pi   = (const float*)d_in[1];
    const float* cen  = (const float*)d_in[2];
    const float* bnd  = (const float*)d_in[3];
    float* out = (float*)d_out;
    const int n_rows = in_sizes[0] / D;   // 524288
    tq_kernel<<<4096, 256, 0, stream>>>(x, Pi, cen, bnd, out, n_rows);
}

// Round 2
// 883.460 us; speedup vs baseline: 3.2006x; 1.5283x over previous
//
#include <hip/hip_runtime.h>
#include <hip/hip_fp16.h>

#define D 128
#define RT 16           // rows per block-iteration (one 16x16 MFMA M-tile)
#define XP 132          // padded LDS row stride (floats / u32) - kills 16-way bank conflict
#define TRIG 8e-6f      // fp64-recompute trigger (split-bf16 fast path error ~2e-6)
#define REL_W 2e-6      // blend band half-width, relative to |boundary|
#define TS 0.3          // plateau fraction of band

typedef __attribute__((ext_vector_type(8))) short short8;
typedef __attribute__((ext_vector_type(4))) float f32x4;
typedef __attribute__((ext_vector_type(4))) unsigned int u32x4;

#define MFMA(a, b, c) __builtin_amdgcn_mfma_f32_16x16x32_bf16( \
    __builtin_bit_cast(short8, (a)), __builtin_bit_cast(short8, (b)), (c), 0, 0, 0)

// truncate float to bf16-representable (top 16 bits); residual subtraction is exact
__device__ __forceinline__ float tb16(float x) {
    return __uint_as_float(__float_as_uint(x) & 0xffff0000u);
}
// pack bf16(lo), bf16(hi) -> u32 (element order: lo = even k, hi = odd k)
__device__ __forceinline__ unsigned pk(float lo, float hi) {
    return (__float_as_uint(lo) >> 16) | (__float_as_uint(hi) & 0xffff0000u);
}

// Forward: Y[r][c] = sum_k X[r][k] * Pi[c][k]   (A = X, B = Pi^T, k-contiguous in Pi rows)
//   split-bf16 x (3 terms) x Pi (3 terms): products 11,12,21,13,22,31 -> eps ~2e-6 << TRIG
// Recon:   Z[r][m] = sum_c Q[r][c] * Pi[c][m]   (A = Q, B = Pi, 2x2-term, 3 products)
// Fragment layout (gfx950 16x16x32 bf16):
//   A: lane l holds A[l&15][(l>>4)*8 + e], e=0..7, packed 2/VGPR (even lo, odd hi)
//   B: lane l holds B[(l>>4)*8 + e][l&15]
//   C: lane l holds C[(l>>4)*4 + reg][l&15]   (verified layout)
__global__ __launch_bounds__(256, 2) void tq_kernel(
    const float* __restrict__ x, const float* __restrict__ Pi,
    const float* __restrict__ centroids, const float* __restrict__ boundaries,
    float* __restrict__ out, int n_rows)
{
    __shared__ __align__(16) float    xls[2][RT * XP];  // exact fp32 rows (double-buffered)
    __shared__ __align__(16) unsigned qls[RT * XP];     // packed (q_hi|q_lo) bf16 pairs
    __shared__ double s_norm2[RT];
    __shared__ double s_dend[RT];
    __shared__ float  s_invnf[RT];
    __shared__ float  s_n16[RT];
    __shared__ float  cbuf[16];
    __shared__ float  fbp[18];       // padded inner boundaries (fp32, +/-inf sentinels)
    __shared__ double dbuf[15];      // inner boundaries (fp64, slow path)

    const int tid  = threadIdx.x;
    const int lane = tid & 63;
    const int wv   = tid >> 6;        // wave 0..3 -> coord slice [wv*32, wv*32+32)
    const int l15  = lane & 15;
    const int l4   = lane >> 4;       // lane quarter 0..3
    const int lrow = tid >> 4;        // loader: row 0..15
    const int lcol = (tid & 15) * 8;  // loader: 8-float chunk

    // ---- one-time: Pi fragments in registers (ALL indices compile-time after unroll) ----
    u32x4 pBf[3][2][4];   // [split term][n-tile][k-step]  forward B = Pi^T
    u32x4 pBr[2][2][4];   // [split term][n-tile][k-step]  recon   B = Pi
    #pragma unroll
    for (int nt = 0; nt < 2; ++nt) {
        const int c = wv * 32 + nt * 16 + l15;   // this lane's coord / output column
        #pragma unroll
        for (int ks = 0; ks < 4; ++ks) {
            const int kb = ks * 32 + l4 * 8;
            const float* prow = Pi + c * D + kb;           // k-contiguous
            #pragma unroll
            for (int ir = 0; ir < 4; ++ir) {
                float a = prow[2 * ir], b = prow[2 * ir + 1];
                float a1 = tb16(a),           b1 = tb16(b);
                float a2 = tb16(a - a1),      b2 = tb16(b - b1);
                float a3 = tb16(a - a1 - a2), b3 = tb16(b - b1 - b2);
                pBf[0][nt][ks][ir] = pk(a1, b1);
                pBf[1][nt][ks][ir] = pk(a2, b2);
                pBf[2][nt][ks][ir] = pk(a3, b3);
            }
            #pragma unroll
            for (int ir = 0; ir < 4; ++ir) {               // B[k][m] = Pi[k*D + m], strided
                float a = Pi[(kb + 2 * ir) * D + c];
                float b = Pi[(kb + 2 * ir + 1) * D + c];
                float a1 = tb16(a),      b1 = tb16(b);
                float a2 = tb16(a - a1), b2 = tb16(b - b1);
                pBr[0][nt][ks][ir] = pk(a1, b1);
                pBr[1][nt][ks][ir] = pk(a2, b2);
            }
        }
    }

    float bnd[15];    // uniform -> SGPRs
    #pragma unroll
    for (int i = 0; i < 15; ++i) bnd[i] = boundaries[i + 1];
    if (tid < 16) cbuf[tid] = centroids[tid];
    if (tid < 15) { dbuf[tid] = (double)boundaries[tid + 1]; fbp[tid + 1] = boundaries[tid + 1]; }
    if (tid == 0) { fbp[0] = -3.0e38f; fbp[16] = 3.0e38f; }

    const long long rstride = (long long)gridDim.x * RT;
    long long rb = (long long)blockIdx.x * RT;

    // prologue prefetch
    float4 g0, g1;
    if (rb < n_rows) {
        long long lr = rb + lrow; if (lr >= n_rows) lr = n_rows - 1;
        const float* px = x + lr * D + lcol;
        g0 = *(const float4*)(px);
        g1 = *(const float4*)(px + 4);
    }
    int buf = 0;

    for (; rb < n_rows; rb += rstride) {
        float* xb = xls[buf];

        // ---- phase 1: stage rows + fp64 norm^2 (16 threads/row, width-16 shfl) ----
        *(float4*)(xb + lrow * XP + lcol)     = g0;
        *(float4*)(xb + lrow * XP + lcol + 4) = g1;
        double dp = (double)g0.x * g0.x + (double)g0.y * g0.y
                  + (double)g0.z * g0.z + (double)g0.w * g0.w
                  + (double)g1.x * g1.x + (double)g1.y * g1.y
                  + (double)g1.z * g1.z + (double)g1.w * g1.w;
        #pragma unroll
        for (int off = 8; off; off >>= 1)
            dp += __shfl_down(dp, off, 16);
        if ((tid & 15) == 0) s_norm2[lrow] = dp;
        __syncthreads();   // B1: xbuf + norm2 visible

        // prefetch next iteration's rows (latency hidden under MFMA phases)
        {
            long long rbn = rb + rstride;
            if (rbn < n_rows) {
                long long lr = rbn + lrow; if (lr >= n_rows) lr = n_rows - 1;
                const float* px = x + lr * D + lcol;
                g0 = *(const float4*)(px);
                g1 = *(const float4*)(px + 4);
            }
        }

        // ---- phase 1b: per-row norm constants (threads 0..15) ----
        if (tid < RT) {
            double nrm = sqrt(s_norm2[tid]);
            double den = nrm + 1e-8;
            s_dend[tid]  = den;
            s_invnf[tid] = (float)(1.0 / den);
            // correctly-rounded fp64 -> fp16 (avoid double rounding via fp32)
            __half h0 = __float2half((float)nrm);
            unsigned short hb = __half_as_ushort(h0);
            unsigned short bestb = hb;
            double bestd = fabs((double)__half2float(h0) - nrm);
            #pragma unroll
            for (int k = 0; k < 2; ++k) {
                unsigned short cb = (unsigned short)(k == 0 ? hb - 1 : hb + 1);
                double v2 = (double)__half2float(__ushort_as_half(cb));
                double dd = fabs(v2 - nrm);
                if (dd < bestd || (dd == bestd && ((cb & 1) == 0) && ((bestb & 1) == 1))) {
                    bestd = dd; bestb = cb;
                }
            }
            s_n16[tid] = __half2float(__ushort_as_half(bestb));
        }

        // ---- phase 2: forward MFMA, 6 split products, K=128 in 4 steps ----
        f32x4 accF[2] = {{0.f, 0.f, 0.f, 0.f}, {0.f, 0.f, 0.f, 0.f}};
        #pragma unroll
        for (int ks = 0; ks < 4; ++ks) {
            const float* xp = xb + l15 * XP + ks * 32 + l4 * 8;
            float4 v0 = *(const float4*)(xp);
            float4 v1 = *(const float4*)(xp + 4);
            float e[8] = {v0.x, v0.y, v0.z, v0.w, v1.x, v1.y, v1.z, v1.w};
            u32x4 xa[3];
            #pragma unroll
            for (int ir = 0; ir < 4; ++ir) {
                float a = e[2 * ir], b = e[2 * ir + 1];
                float a1 = tb16(a),           b1 = tb16(b);
                float a2 = tb16(a - a1),      b2 = tb16(b - b1);
                float a3 = tb16(a - a1 - a2), b3 = tb16(b - b1 - b2);
                xa[0][ir] = pk(a1, b1);
                xa[1][ir] = pk(a2, b2);
                xa[2][ir] = pk(a3, b3);
            }
            accF[0] = MFMA(xa[0], pBf[0][0][ks], accF[0]);
            accF[1] = MFMA(xa[0], pBf[0][1][ks], accF[1]);
            accF[0] = MFMA(xa[0], pBf[1][0][ks], accF[0]);
            accF[1] = MFMA(xa[0], pBf[1][1][ks], accF[1]);
            accF[0] = MFMA(xa[1], pBf[0][0][ks], accF[0]);
            accF[1] = MFMA(xa[1], pBf[0][1][ks], accF[1]);
            accF[0] = MFMA(xa[0], pBf[2][0][ks], accF[0]);
            accF[1] = MFMA(xa[0], pBf[2][1][ks], accF[1]);
            accF[0] = MFMA(xa[1], pBf[1][0][ks], accF[0]);
            accF[1] = MFMA(xa[1], pBf[1][1][ks], accF[1]);
            accF[0] = MFMA(xa[2], pBf[0][0][ks], accF[0]);
            accF[1] = MFMA(xa[2], pBf[0][1][ks], accF[1]);
        }
        __syncthreads();   // B2: s_invnf/s_dend/s_n16 visible

        // ---- phase 3: binning on C-fragments (lane owns 4 rows x 2 coords) ----
        #pragma unroll
        for (int nt = 0; nt < 2; ++nt) {
            const int c = wv * 32 + nt * 16 + l15;
            #pragma unroll
            for (int j = 0; j < 4; ++j) {
                const int r = l4 * 4 + j;
                const float rcf = accF[nt][j] * s_invnf[r];
                int idx = 0;
                #pragma unroll
                for (int i = 0; i < 15; ++i) idx += (bnd[i] < rcf) ? 1 : 0;
                const float mind = fminf(rcf - fbp[idx], fbp[idx + 1] - rcf);
                float qv;
                if (__builtin_expect(mind < TRIG, 0)) {
                    // exact fp64 recompute of this coordinate (rare)
                    double s0 = 0.0, s1 = 0.0, s2 = 0.0, s3 = 0.0;
                    const float* pim = Pi + c * D;
                    const float* xr  = xb + r * XP;
                    for (int d2 = 0; d2 < D; d2 += 4) {
                        s0 += (double)xr[d2]     * (double)pim[d2];
                        s1 += (double)xr[d2 + 1] * (double)pim[d2 + 1];
                        s2 += (double)xr[d2 + 2] * (double)pim[d2 + 2];
                        s3 += (double)xr[d2 + 3] * (double)pim[d2 + 3];
                    }
                    double rc = ((s0 + s1) + (s2 + s3)) / s_dend[r];
                    int idx2 = 0; int ib = 0; double mind2 = 1e30;
                    #pragma unroll
                    for (int i = 0; i < 15; ++i) {
                        double b = dbuf[i];
                        idx2 += (b < rc) ? 1 : 0;
                        double dd = fabs(rc - b);
                        if (dd < mind2) { mind2 = dd; ib = i; }
                    }
                    double w = REL_W * fabs(dbuf[ib]);
                    if (mind2 < w) {
                        // ambiguous zone: blend adjacent centroids
                        double t  = (rc - dbuf[ib]) / w;
                        double at = fabs(t);
                        double u;
                        if (at <= TS) u = 0.5;
                        else {
                            double v2 = 0.5 * (at - TS) / (1.0 - TS);
                            u = (t > 0.0) ? 0.5 + v2 : 0.5 - v2;
                        }
                        qv = (float)((1.0 - u) * (double)cbuf[ib] + u * (double)cbuf[ib + 1]);
                    } else {
                        qv = cbuf[idx2];
                    }
                } else {
                    qv = cbuf[idx];
                }
                float q1 = tb16(qv);
                qls[r * XP + c] = pk(q1, qv - q1);   // lo = hi-term, hi = residual
            }
        }
        __syncthreads();   // B3: qls visible

        // ---- phase 4: recon MFMA, 3 split products ----
        f32x4 accR[2] = {{0.f, 0.f, 0.f, 0.f}, {0.f, 0.f, 0.f, 0.f}};
        #pragma unroll
        for (int ks = 0; ks < 4; ++ks) {
            const unsigned* qp = qls + l15 * XP + ks * 32 + l4 * 8;
            u32x4 qa = *(const u32x4*)(qp);
            u32x4 qb = *(const u32x4*)(qp + 4);
            unsigned u[8] = {qa[0], qa[1], qa[2], qa[3], qb[0], qb[1], qb[2], qb[3]};
            u32x4 f1, f2;
            #pragma unroll
            for (int ir = 0; ir < 4; ++ir) {
                f1[ir] = (u[2 * ir] & 0xffffu) | (u[2 * ir + 1] << 16);
                f2[ir] = (u[2 * ir] >> 16)    | (u[2 * ir + 1] & 0xffff0000u);
            }
            accR[0] = MFMA(f1, pBr[0][0][ks], accR[0]);
            accR[1] = MFMA(f1, pBr[0][1][ks], accR[1]);
            accR[0] = MFMA(f2, pBr[0][0][ks], accR[0]);
            accR[1] = MFMA(f2, pBr[0][1][ks], accR[1]);
            accR[0] = MFMA(f1, pBr[1][0][ks], accR[0]);
            accR[1] = MFMA(f1, pBr[1][1][ks], accR[1]);
        }

        // ---- phase 5: scale by fp16-rounded norm, store ----
        #pragma unroll
        for (int j = 0; j < 4; ++j) {
            const int r = l4 * 4 + j;
            const long long grow = rb + r;
            if (grow < n_rows) {
                const float n16v = s_n16[r];
                out[grow * D + wv * 32 + l15]      = accR[0][j] * n16v;
                out[grow * D + wv * 32 + 16 + l15] = accR[1][j] * n16v;
            }
        }
        buf ^= 1;
        // no end barrier needed: next qls write is after B2 of next iter,
        // next xls[buf] write targets the buffer unused this iter.
    }
}

extern "C" void kernel_launch(void* const* d_in, const int* in_sizes, int n_in,
                              void* d_out, int out_size, void* d_ws, size_t ws_size,
                              hipStream_t stream) {
    const float* x    = (const float*)d_in[0];
    const float* Pi   = (const float*)d_in[1];
    const float* cen  = (const float*)d_in[2];
    const float* bnd  = (const float*)d_in[3];
    float* out = (float*)d_out;
    const int n_rows = in_sizes[0] / D;   // 524288
    tq_kernel<<<4096, 256, 0, stream>>>(x, Pi, cen, bnd, out, n_rows);
}